// Round 1
// baseline (443.150 us; speedup 1.0000x reference)
//
#include <hip/hip_runtime.h>
#include <hip/hip_bf16.h>
#include <stdint.h>

// Problem constants (from setup_inputs): B=8192, D_in=1024, H=2048
#define B_DIM 8192
#define D_IN  1024
#define H_DIM 2048
#define K_DIM (D_IN + H_DIM)   // 3072: A = [x | u], Wc = [win | wr]

#define ALPHA_U (1.0f/10.0f)
#define ALPHA_V (1.0f/150.0f)
#define M_CONST 10.0f

typedef __attribute__((ext_vector_type(8))) short short8;   // 8 bf16 = 4 VGPRs
typedef __attribute__((ext_vector_type(4))) float floatx4;

// ---------------------------------------------------------------------------
// fp32 -> bf16 (RNE) pack into workspace, building concatenated K layout.
// i indexes float4 groups of the source; dst row stride / col offset place the
// block into the [rows][3072] bf16 matrix.
// ---------------------------------------------------------------------------
__device__ __forceinline__ unsigned short f2bf(float f) {
    union { float f; unsigned u; } x; x.f = f;
    unsigned r = x.u + 0x7fffu + ((x.u >> 16) & 1u);
    return (unsigned short)(r >> 16);
}

__global__ void pack_bf16(const float4* __restrict__ src, unsigned short* __restrict__ dst,
                          int shift, int mask, int col_off, int total4) {
    int i = blockIdx.x * blockDim.x + threadIdx.x;
    if (i >= total4) return;
    int idx = i << 2;                 // element index in src
    int r = idx >> shift;             // src row (src_cols = 1<<shift)
    int c = idx & mask;               // src col
    float4 f = src[i];
    ushort4 o;
    o.x = f2bf(f.x); o.y = f2bf(f.y); o.z = f2bf(f.z); o.w = f2bf(f.w);
    *(ushort4*)(dst + (size_t)r * K_DIM + col_off + c) = o;
}

// ---------------------------------------------------------------------------
// Fused GEMM: C = A(8192x3072) * Wc(2048x3072)^T, bf16 in, fp32 accumulate,
// epilogue computes v_new and u_new and writes both outputs.
// m97 structure: 128x128 tile, BK=32, 4 waves (2x2) each 64x64 via 4x4 of
// mfma_f32_16x16x32_bf16; global_load_lds width=16 staging (lane-ordered).
// ---------------------------------------------------------------------------
#define GLOAD_LDS16(gp, lp)                                                          \
    __builtin_amdgcn_global_load_lds(                                                \
        (const __attribute__((address_space(1))) unsigned int*)(gp),                 \
        (__attribute__((address_space(3))) unsigned int*)(lp), 16, 0, 0)

__global__ __launch_bounds__(256)
void gemm_fused(const unsigned short* __restrict__ A,   // [8192][3072] bf16
                const unsigned short* __restrict__ Wc,  // [2048][3072] bf16
                const float* __restrict__ u_in,         // [8192][2048]
                const float* __restrict__ v_in,         // [8192][2048]
                const float* __restrict__ bias,         // [2048]
                float* __restrict__ out)                // [u_new | v_new]
{
    __shared__ __align__(16) unsigned short As[128 * 32];
    __shared__ __align__(16) unsigned short Bs[128 * 32];

    const int tid  = threadIdx.x;
    const int wave = tid >> 6;
    const int lane = tid & 63;
    const int bm = blockIdx.y;   // M tile (64 tiles)
    const int bn = blockIdx.x;   // N tile (16 tiles)

    // Staging: each wave fills 2 contiguous 1024B chunks of As and Bs.
    // Chunk c covers tile rows [c*16, c*16+16); lane l -> row c*16 + l/4,
    // col (l&3)*8 bf16.  LDS dest is wave-uniform base + lane*16 (HW rule).
    const int srow = lane >> 2;          // 0..15
    const int scol = (lane & 3) * 8;     // 0,8,16,24
    const unsigned short* Ag = A  + (size_t)(bm * 128 + wave * 32 + srow) * K_DIM + scol;
    const unsigned short* Bg = Wc + (size_t)(bn * 128 + wave * 32 + srow) * K_DIM + scol;
    unsigned short* AsW = As + wave * 1024;   // 2 chunks = 1024 shorts
    unsigned short* BsW = Bs + wave * 1024;

    // Compute-side fragment addressing
    const int wm = (wave >> 1) * 64;     // wave's M origin in tile
    const int wn = (wave & 1) * 64;      // wave's N origin in tile
    const int frow = lane & 15;          // fragment row (m or n)
    const int fk   = (lane >> 4) * 8;    // fragment k offset (quad*8)

    floatx4 acc[4][4] = {};

    for (int k0 = 0; k0 < K_DIM; k0 += 32) {
        GLOAD_LDS16(Ag + k0,              AsW);
        GLOAD_LDS16(Ag + 16 * K_DIM + k0, AsW + 512);
        GLOAD_LDS16(Bg + k0,              BsW);
        GLOAD_LDS16(Bg + 16 * K_DIM + k0, BsW + 512);
        __syncthreads();

        short8 af[4], bfr[4];
#pragma unroll
        for (int i = 0; i < 4; i++)
            af[i] = *(const short8*)&As[(wm + i * 16 + frow) * 32 + fk];
#pragma unroll
        for (int j = 0; j < 4; j++)
            bfr[j] = *(const short8*)&Bs[(wn + j * 16 + frow) * 32 + fk];

#pragma unroll
        for (int i = 0; i < 4; i++)
#pragma unroll
            for (int j = 0; j < 4; j++)
                acc[i][j] = __builtin_amdgcn_mfma_f32_16x16x32_bf16(
                    af[i], bfr[j], acc[i][j], 0, 0, 0);
        __syncthreads();
    }

    // Epilogue: C/D layout col = lane&15, row = (lane>>4)*4 + reg
    const size_t outV = (size_t)B_DIM * H_DIM;
    const int rbase = (lane >> 4) * 4;
    const int cbase = lane & 15;
#pragma unroll
    for (int i = 0; i < 4; i++) {
#pragma unroll
        for (int j = 0; j < 4; j++) {
            const int col = bn * 128 + wn + j * 16 + cbase;
            const float bcol = bias[col];
#pragma unroll
            for (int r = 0; r < 4; r++) {
                const int row = bm * 128 + wm + i * 16 + rbase + r;
                const size_t idx = (size_t)row * H_DIM + col;
                const float uu = u_in[idx];
                const float vv = v_in[idx];
                const float vn = fmaxf((1.0f - ALPHA_V) * vv + (ALPHA_V * M_CONST) * uu, 0.0f);
                const float drive = acc[i][j][r] + bcol - vn;
                const float un = fmaxf((1.0f - ALPHA_U) * uu + ALPHA_U * drive, 0.0f);
                out[idx] = un;
                out[outV + idx] = vn;
            }
        }
    }
}

// ---------------------------------------------------------------------------
extern "C" void kernel_launch(void* const* d_in, const int* in_sizes, int n_in,
                              void* d_out, int out_size, void* d_ws, size_t ws_size,
                              hipStream_t stream) {
    const float* x    = (const float*)d_in[0];
    const float* u    = (const float*)d_in[1];
    const float* v    = (const float*)d_in[2];
    const float* win  = (const float*)d_in[3];
    const float* wr   = (const float*)d_in[4];
    const float* bias = (const float*)d_in[5];
    float* out = (float*)d_out;

    // Workspace layout: A bf16 [8192][3072], then Wc bf16 [2048][3072]
    unsigned short* Abf = (unsigned short*)d_ws;
    unsigned short* Wbf = Abf + (size_t)B_DIM * K_DIM;

    const int threads = 256;
    // x -> A[:, 0:1024]
    {
        int total4 = (B_DIM * D_IN) / 4;
        pack_bf16<<<total4 / threads, threads, 0, stream>>>(
            (const float4*)x, Abf, 10, 1023, 0, total4);
    }
    // u -> A[:, 1024:3072]
    {
        int total4 = (B_DIM * H_DIM) / 4;
        pack_bf16<<<total4 / threads, threads, 0, stream>>>(
            (const float4*)u, Abf, 11, 2047, D_IN, total4);
    }
    // win -> Wc[:, 0:1024]
    {
        int total4 = (H_DIM * D_IN) / 4;
        pack_bf16<<<total4 / threads, threads, 0, stream>>>(
            (const float4*)win, Wbf, 10, 1023, 0, total4);
    }
    // wr -> Wc[:, 1024:3072]
    {
        int total4 = (H_DIM * H_DIM) / 4;
        pack_bf16<<<total4 / threads, threads, 0, stream>>>(
            (const float4*)wr, Wbf, 11, 2047, D_IN, total4);
    }

    dim3 grid(H_DIM / 128, B_DIM / 128);   // (16, 64)
    gemm_fused<<<grid, 256, 0, stream>>>(Abf, Wbf, u, v, bias, out);
}

// Round 2
// 401.512 us; speedup vs baseline: 1.1037x; 1.1037x over previous
//
#include <hip/hip_runtime.h>
#include <hip/hip_bf16.h>
#include <stdint.h>

// Problem constants (from setup_inputs): B=8192, D_in=1024, H=2048
#define B_DIM 8192
#define D_IN  1024
#define H_DIM 2048
#define K_DIM (D_IN + H_DIM)   // 3072: A = [x | u], Wc = [win | wr]

#define CV_CONST  (1.0f - 1.0f/150.0f)   // (1-ALPHA_V)
#define CUV_CONST (10.0f/150.0f)         // ALPHA_V*M
#define CU_CONST  0.9f                   // (1-ALPHA_U)
#define AU_CONST  0.1f                   // ALPHA_U

typedef __attribute__((ext_vector_type(8))) short short8;   // 8 bf16 = 4 VGPRs
typedef __attribute__((ext_vector_type(4))) float floatx4;

__device__ __forceinline__ unsigned short f2bf(float f) {
    union { float f; unsigned u; } x; x.f = f;
    unsigned r = x.u + 0x7fffu + ((x.u >> 16) & 1u);
    return (unsigned short)(r >> 16);
}

// ---------------------------------------------------------------------------
// Single fused pack: x,u -> Abf[8192][3072]; win,wr -> Wbf[2048][3072], bf16 RNE.
// One launch instead of four (launch overhead was ~half the wall time in R1).
// ---------------------------------------------------------------------------
#define N4_X   ((B_DIM * D_IN)  / 4)   // 2097152
#define N4_U   ((B_DIM * H_DIM) / 4)   // 4194304
#define N4_WIN ((H_DIM * D_IN)  / 4)   //  524288
#define N4_WR  ((H_DIM * H_DIM) / 4)   // 1048576
#define N4_TOT (N4_X + N4_U + N4_WIN + N4_WR)   // 7864320 (= 30720 * 256)

__global__ __launch_bounds__(256)
void pack_all(const float4* __restrict__ x, const float4* __restrict__ u,
              const float4* __restrict__ win, const float4* __restrict__ wr,
              unsigned short* __restrict__ Abf, unsigned short* __restrict__ Wbf) {
    int i = blockIdx.x * 256 + threadIdx.x;
    const float4* src; unsigned short* dst; int shift, mask, coloff;
    if (i < N4_X)                    { src = x;   dst = Abf; shift = 10; mask = 1023; coloff = 0;    }
    else if (i < N4_X + N4_U)        { i -= N4_X; src = u;   dst = Abf; shift = 11; mask = 2047; coloff = D_IN; }
    else if (i < N4_X + N4_U + N4_WIN){ i -= N4_X + N4_U; src = win; dst = Wbf; shift = 10; mask = 1023; coloff = 0; }
    else                             { i -= N4_X + N4_U + N4_WIN; src = wr; dst = Wbf; shift = 11; mask = 2047; coloff = D_IN; }
    int idx = i << 2;
    int r = idx >> shift;
    int c = idx & mask;
    float4 f = src[i];
    ushort4 o;
    o.x = f2bf(f.x); o.y = f2bf(f.y); o.z = f2bf(f.z); o.w = f2bf(f.w);
    *(ushort4*)(dst + (size_t)r * K_DIM + coloff + c) = o;
}

// ---------------------------------------------------------------------------
// Fused GEMM: C = A(8192x3072) * Wc(2048x3072)^T, bf16 in, fp32 acc.
// m97 structure + (a) swizzled LDS k-group slots to kill the 8-way ds_read_b128
// bank conflict, (b) LDS-transposed float4 epilogue, (c) XCD block swizzle.
// ---------------------------------------------------------------------------
#define GLOAD_LDS16(gp, lp)                                                          \
    __builtin_amdgcn_global_load_lds(                                                \
        (const __attribute__((address_space(1))) unsigned int*)(gp),                 \
        (__attribute__((address_space(3))) unsigned int*)(lp), 16, 0, 0)

// Es scratch: per (wave, parity) region of 16 rows x 68 floats (pad 68 -> +4 bank
// rotation per row; read pattern is bank-balanced). 8 regions * 4352 B = 34816 B.
#define ES_STRIDE 68
#define ES_REGION (16 * ES_STRIDE)          // 1088 floats
#define SMEM_BYTES (8 * ES_REGION * 4)      // 34816 >= 16384 (K-loop As+Bs)

__global__ __launch_bounds__(256, 4)
void gemm_fused(const unsigned short* __restrict__ A,   // [8192][3072] bf16
                const unsigned short* __restrict__ Wc,  // [2048][3072] bf16
                const float* __restrict__ u_in,         // [8192][2048]
                const float* __restrict__ v_in,         // [8192][2048]
                const float* __restrict__ bias,         // [2048]
                float* __restrict__ out)                // [u_new | v_new]
{
    __shared__ __align__(16) unsigned char smem_raw[SMEM_BYTES];
    unsigned short* As = (unsigned short*)smem_raw;        // 128x32 bf16 = 8 KB
    unsigned short* Bs = As + 128 * 32;                    // 8 KB
    float* Esf = (float*)smem_raw;                         // epilogue scratch (aliases)

    const int tid  = threadIdx.x;
    const int wave = tid >> 6;
    const int lane = tid & 63;

    // XCD swizzle: assume consecutive blockIdx round-robin XCDs; give XCD k a
    // contiguous band of 8 bm rows so co-resident blocks share A-tile rows in L2.
    const int bid = blockIdx.x;
    const int wid = ((bid & 7) << 7) | (bid >> 3);
    const int bm = wid >> 4;     // 0..63
    const int bn = wid & 15;     // 0..15

    // --- staging: lane l -> row l>>2 (of 16-row chunk), LDS slot l&3.
    // Swizzle: slot s of row r holds k-group (s - (r>>1))&3, so lane carries:
    const int srow = lane >> 2;
    const int gcar = ((lane & 3) - ((lane >> 3) & 3)) & 3;
    const int scol = gcar * 8;   // elements
    const unsigned short* Ag = A  + (size_t)(bm * 128 + wave * 32 + srow) * K_DIM + scol;
    const unsigned short* Bg = Wc + (size_t)(bn * 128 + wave * 32 + srow) * K_DIM + scol;
    unsigned short* AsW = As + wave * 1024;
    unsigned short* BsW = Bs + wave * 1024;

    // --- compute-side fragment addressing (with matching swizzle)
    const int wm = (wave >> 1) * 64;
    const int wn = (wave & 1) * 64;
    const int frow = lane & 15;
    const int g    = lane >> 4;                       // k-group 0..3
    const int swz  = ((g + (frow >> 1)) & 3) * 8;     // swizzled element offset

    floatx4 acc[4][4] = {};

    for (int k0 = 0; k0 < K_DIM; k0 += 32) {
        GLOAD_LDS16(Ag + k0,              AsW);
        GLOAD_LDS16(Ag + 16 * K_DIM + k0, AsW + 512);
        GLOAD_LDS16(Bg + k0,              BsW);
        GLOAD_LDS16(Bg + 16 * K_DIM + k0, BsW + 512);
        __syncthreads();

        short8 af[4], bfr[4];
#pragma unroll
        for (int i = 0; i < 4; i++)
            af[i] = *(const short8*)&As[(wm + i * 16 + frow) * 32 + swz];
#pragma unroll
        for (int j = 0; j < 4; j++)
            bfr[j] = *(const short8*)&Bs[(wn + j * 16 + frow) * 32 + swz];

#pragma unroll
        for (int i = 0; i < 4; i++)
#pragma unroll
            for (int j = 0; j < 4; j++)
                acc[i][j] = __builtin_amdgcn_mfma_f32_16x16x32_bf16(
                    af[i], bfr[j], acc[i][j], 0, 0, 0);
        __syncthreads();
    }

    // --- epilogue: transpose each 16x64 i-slice through LDS, then float4 I/O.
    // C/D layout: col = lane&15, row = (lane>>4)*4 + reg.
    const int q   = lane >> 4;        // 0..3
    const int c16 = lane & 15;
    const int rbase = q * 4;
    const int colg = bn * 128 + wn + c16 * 4;
    const float4 b4 = *(const float4*)&bias[colg];
    const size_t outV = (size_t)B_DIM * H_DIM;

#pragma unroll
    for (int i = 0; i < 4; i++) {
        float* Es = Esf + (wave * 2 + (i & 1)) * ES_REGION;
        // stage acc slice i (b32 writes, 2 lanes/bank -> conflict-free)
#pragma unroll
        for (int j = 0; j < 4; j++)
#pragma unroll
            for (int r = 0; r < 4; r++)
                Es[(rbase + r) * ES_STRIDE + j * 16 + c16] = acc[i][j][r];
        // consume: 4 rows x 64 cols per pass, fully 256B-coalesced
#pragma unroll
        for (int rg = 0; rg < 4; rg++) {
            const int rloc = rg * 4 + q;
            const float4 a4 = *(const float4*)&Es[rloc * ES_STRIDE + c16 * 4];
            const size_t idx = (size_t)(bm * 128 + wm + i * 16 + rloc) * H_DIM + colg;
            const float4 u4 = *(const float4*)&u_in[idx];
            const float4 v4 = *(const float4*)&v_in[idx];
            float4 vn, un;
            vn.x = fmaxf(CV_CONST * v4.x + CUV_CONST * u4.x, 0.0f);
            vn.y = fmaxf(CV_CONST * v4.y + CUV_CONST * u4.y, 0.0f);
            vn.z = fmaxf(CV_CONST * v4.z + CUV_CONST * u4.z, 0.0f);
            vn.w = fmaxf(CV_CONST * v4.w + CUV_CONST * u4.w, 0.0f);
            un.x = fmaxf(CU_CONST * u4.x + AU_CONST * (a4.x + b4.x - vn.x), 0.0f);
            un.y = fmaxf(CU_CONST * u4.y + AU_CONST * (a4.y + b4.y - vn.y), 0.0f);
            un.z = fmaxf(CU_CONST * u4.z + AU_CONST * (a4.z + b4.z - vn.z), 0.0f);
            un.w = fmaxf(CU_CONST * u4.w + AU_CONST * (a4.w + b4.w - vn.w), 0.0f);
            *(float4*)&out[idx]        = un;
            *(float4*)&out[outV + idx] = vn;
        }
    }
}

// ---------------------------------------------------------------------------
extern "C" void kernel_launch(void* const* d_in, const int* in_sizes, int n_in,
                              void* d_out, int out_size, void* d_ws, size_t ws_size,
                              hipStream_t stream) {
    const float* x    = (const float*)d_in[0];
    const float* u    = (const float*)d_in[1];
    const float* v    = (const float*)d_in[2];
    const float* win  = (const float*)d_in[3];
    const float* wr   = (const float*)d_in[4];
    const float* bias = (const float*)d_in[5];
    float* out = (float*)d_out;

    unsigned short* Abf = (unsigned short*)d_ws;
    unsigned short* Wbf = Abf + (size_t)B_DIM * K_DIM;

    pack_all<<<N4_TOT / 256, 256, 0, stream>>>(
        (const float4*)x, (const float4*)u, (const float4*)win, (const float4*)wr,
        Abf, Wbf);

    gemm_fused<<<1024, 256, 0, stream>>>(Abf, Wbf, u, v, bias, out);
}